// Round 6
// baseline (265.478 us; speedup 1.0000x reference)
//
#include <hip/hip_runtime.h>
#include <math.h>

#define E_  8
#define H_  2048
#define I_  768
#define T_  1024
#define K_  2
#define TK_ 2048
#define GU_ 1536   // 2*I

typedef short  short8 __attribute__((ext_vector_type(8)));
typedef __bf16 bf16x8 __attribute__((ext_vector_type(8)));
typedef float  f32x4  __attribute__((ext_vector_type(4)));

static __device__ __forceinline__ short f2bf(float f) {
  union { float f; unsigned u; } v; v.f = f;
  unsigned r = (v.u + 0x7fffu + ((v.u >> 16) & 1u)) >> 16;
  return (short)r;
}

// pack two floats -> two bf16 in one u32 (round-half-up + v_perm)
static __device__ __forceinline__ unsigned pk2bf(float a, float b) {
  unsigned ua = __float_as_uint(a) + 0x8000u;
  unsigned ub = __float_as_uint(b) + 0x8000u;
  return __builtin_amdgcn_perm(ub, ua, 0x07060302u);  // lo=hi16(ua), hi=hi16(ub)
}

#define GLOAD_LDS16(g, l)                                                   \
  __builtin_amdgcn_global_load_lds(                                         \
      (const __attribute__((address_space(1))) void*)(g),                   \
      (__attribute__((address_space(3))) void*)(l), 16, 0, 0)

#define MFMA_BF16_16x16x32 __builtin_amdgcn_mfma_f32_16x16x32_bf16

// fragment read: row-major [row][64], phys octet = oct ^ (row&7); b128,
// 2-way bank aliasing max (free).
static __device__ __forceinline__ bf16x8 frag_ld(const unsigned short* base,
                                                 int row, int oct) {
  return *(const bf16x8*)(base + row * 64 + ((oct ^ (row & 7)) * 8));
}

// B transpose-write at k-quad granularity into the same XOR-octet layout:
// quad q (4 k) of row n lands at phys quad q ^ ((n&7)<<1)  (even XOR keeps
// quad pairs adjacent so frag_ld's b128 sees logical octet o = q>>1).
static __device__ __forceinline__ void quad_st(unsigned short* base, int n,
                                               int q, unsigned u0, unsigned u1) {
  int off = n * 64 + ((q ^ ((n & 7) << 1)) * 4);
  *(uint2*)(base + off) = make_uint2(u0, u1);
}

// --------------------------- prep: X cast + out zero + routing --------------
__global__ __launch_bounds__(256) void prep_kernel(
    const float* __restrict__ X, unsigned short* __restrict__ Xb,
    float* __restrict__ out,
    const int* __restrict__ sel, int* __restrict__ offs,
    int* __restrict__ rows) {
  __shared__ int cnt[E_], cur[E_], loff[E_ + 1];
  if (blockIdx.x < 2048) {
    int i = blockIdx.x * 256 + threadIdx.x;     // one float4 each (T*H/4 total)
    float4 v = ((const float4*)X)[i];
    unsigned p0 = pk2bf(v.x, v.y), p1 = pk2bf(v.z, v.w);
    ((uint2*)Xb)[i] = make_uint2(p0, p1);
    ((float4*)out)[i] = make_float4(0.f, 0.f, 0.f, 0.f);
    return;
  }
  int t = threadIdx.x;
  if (t < E_) { cnt[t] = 0; cur[t] = 0; }
  __syncthreads();
  for (int p = t; p < TK_; p += 256) atomicAdd(&cnt[sel[p]], 1);
  __syncthreads();
  if (t == 0) {
    int s = 0;
    for (int e = 0; e < E_; ++e) { loff[e] = s; s += cnt[e]; }
    loff[E_] = s;
  }
  __syncthreads();
  if (t <= E_) offs[t] = loff[t];
  for (int p = t; p < TK_; p += 256) {
    int e = sel[p];
    int pos = loff[e] + atomicAdd(&cur[e], 1);
    rows[pos] = p;
  }
}

#define SLOTS_ 10   // 64-row slots per expert (cap 640 rows; ~17 sigma margin)

// --------------------------------------------------- fc1 (MFMA) + swiglu ----
// BM=64 rows, 32 act cols (B rows: 32 gate + 32 up), BK=64, double-buffer.
// A: bf16 gathered via global_load_lds. B: fp32 [k][n] direct, in-LDS
// transpose+cast into XOR-octet layout (b128 frag reads).
// Grid: x = 24 act-col tiles, y = 8 experts * SLOTS_ row slots.
// Same (x,e), slot+1 -> blockIdx delta 24 == 0 mod 8 -> same XCD (B L2 reuse).
__global__ __launch_bounds__(256) void fc1_mfma(
    const unsigned short* __restrict__ Xb, const float* __restrict__ GUP,
    const int* __restrict__ offs, const int* __restrict__ rows,
    unsigned short* __restrict__ act) {
  __shared__ __align__(16) unsigned short As[2][64 * 64];   // 16 KB
  __shared__ __align__(16) unsigned short Bs[2][64 * 64];   // 16 KB

  int e    = blockIdx.y / SLOTS_;
  int slot = blockIdx.y % SLOTS_;
  int rbeg = offs[e], rend = offs[e + 1];
  int row0 = rbeg + slot * 64;
  if (row0 >= rend) return;
  int c0 = blockIdx.x * 32;

  int tid = threadIdx.x, lane = tid & 63, w = tid >> 6;
  int rl  = lane >> 3;                    // 0..7
  int oc  = (lane & 7) ^ rl;              // A-side global octet swizzle

  // A: wave w stages rows w*16 .. w*16+15 as two glls of 8 rows.
  int arow0 = row0 + w * 16 + rl, arow1 = arow0 + 8;
  int aidx0 = arow0 < rend ? arow0 : rend - 1;
  int aidx1 = arow1 < rend ? arow1 : rend - 1;
  const unsigned short* agp0 = Xb + (size_t)(rows[aidx0] >> 1) * H_ + oc * 8;
  const unsigned short* agp1 = Xb + (size_t)(rows[aidx1] >> 1) * H_ + oc * 8;
  auto issueA = [&](int buf, int k0) {
    GLOAD_LDS16(agp0 + k0, &As[buf][0] + (w * 16) * 64);
    GLOAD_LDS16(agp1 + k0, &As[buf][0] + (w * 16 + 8) * 64);
  };

  // B: thread covers k-quad kt (4 k) x 4 consecutive n; n<32 gate, n>=32 up.
  int kt = tid >> 4, nt = tid & 15;
  int gb = (nt < 8) ? (c0 + nt * 4) : (I_ + c0 + (nt - 8) * 4);
  const float* gupe = GUP + (size_t)e * H_ * GU_ + gb;

  float4 vb[4];
  auto loadB = [&](int k0) {
#pragma unroll
    for (int i = 0; i < 4; ++i)
      vb[i] = *(const float4*)(gupe + (size_t)(k0 + kt * 4 + i) * GU_);
  };
  auto writeB = [&](int buf) {
#pragma unroll
    for (int j = 0; j < 4; ++j) {
      int n = nt * 4 + j;
      unsigned u0 = pk2bf(((const float*)&vb[0])[j], ((const float*)&vb[1])[j]);
      unsigned u1 = pk2bf(((const float*)&vb[2])[j], ((const float*)&vb[3])[j]);
      quad_st(&Bs[buf][0], n, kt, u0, u1);
    }
  };

  int mh = w >> 1, nh = w & 1;            // wave -> (M half, N half)
  int m = lane & 15, qf = lane >> 4;
  f32x4 acc[2][2] = {};                   // [mt][0]=gate, [mt][1]=up

  issueA(0, 0);
  loadB(0);
  writeB(0);
  int cur = 0;
  const int niter = H_ / 64;
#pragma unroll 1
  for (int it = 0; it < niter; ++it) {
    __syncthreads();                      // buf[cur] ready
    if (it + 1 < niter) { issueA(cur ^ 1, (it + 1) * 64); loadB((it + 1) * 64); }
    const unsigned short* a_ = &As[cur][0];
    const unsigned short* b_ = &Bs[cur][0];
#pragma unroll
    for (int kk = 0; kk < 2; ++kk) {
      int o = kk * 4 + qf;
      bf16x8 af0 = frag_ld(a_, mh * 32 + m,      o);
      bf16x8 af1 = frag_ld(a_, mh * 32 + 16 + m, o);
      bf16x8 bg  = frag_ld(b_, nh * 16 + m,      o);
      bf16x8 bu  = frag_ld(b_, 32 + nh * 16 + m, o);
      acc[0][0] = MFMA_BF16_16x16x32(af0, bg, acc[0][0], 0, 0, 0);
      acc[0][1] = MFMA_BF16_16x16x32(af0, bu, acc[0][1], 0, 0, 0);
      acc[1][0] = MFMA_BF16_16x16x32(af1, bg, acc[1][0], 0, 0, 0);
      acc[1][1] = MFMA_BF16_16x16x32(af1, bu, acc[1][1], 0, 0, 0);
    }
    if (it + 1 < niter) writeB(cur ^ 1);
    cur ^= 1;
  }

  // epilogue: act = silu(gate)*up
#pragma unroll
  for (int mt = 0; mt < 2; ++mt)
#pragma unroll
    for (int r = 0; r < 4; ++r) {
      int prow = row0 + mh * 32 + mt * 16 + qf * 4 + r;
      if (prow < rend) {
        float gv = acc[mt][0][r], uv = acc[mt][1][r];
        float a = gv / (1.0f + __expf(-gv)) * uv;
        act[(size_t)prow * I_ + c0 + nh * 16 + m] = (unsigned short)f2bf(a);
      }
    }
}

// ------------------------------------- fc2 (MFMA) + fused weighted combine --
// BM=64, BN=64 out cols, BK=64, double-buffer; epilogue atomics into out.
// Grid: x = 32 col tiles, y = 8 experts * SLOTS_.
__global__ __launch_bounds__(256) void fc2_mfma(
    const unsigned short* __restrict__ act, const float* __restrict__ DWN,
    const float* __restrict__ RW,
    const int* __restrict__ offs, const int* __restrict__ rows,
    float* __restrict__ out) {
  __shared__ __align__(16) unsigned short As[2][64 * 64];
  __shared__ __align__(16) unsigned short Bs[2][64 * 64];

  int e    = blockIdx.y / SLOTS_;
  int slot = blockIdx.y % SLOTS_;
  int rbeg = offs[e], rend = offs[e + 1];
  int row0 = rbeg + slot * 64;
  if (row0 >= rend) return;
  int c0 = blockIdx.x * 64;

  int tid = threadIdx.x, lane = tid & 63, w = tid >> 6;
  int rl  = lane >> 3;
  int oc  = (lane & 7) ^ rl;

  int arow0 = row0 + w * 16 + rl, arow1 = arow0 + 8;
  int aidx0 = arow0 < rend ? arow0 : rend - 1;
  int aidx1 = arow1 < rend ? arow1 : rend - 1;
  const unsigned short* agp0 = act + (size_t)aidx0 * I_ + oc * 8;
  const unsigned short* agp1 = act + (size_t)aidx1 * I_ + oc * 8;
  auto issueA = [&](int buf, int k0) {
    GLOAD_LDS16(agp0 + k0, &As[buf][0] + (w * 16) * 64);
    GLOAD_LDS16(agp1 + k0, &As[buf][0] + (w * 16 + 8) * 64);
  };

  int kt = tid >> 4, nt = tid & 15;
  const float* dwe = DWN + (size_t)e * I_ * H_ + c0 + nt * 4;

  float4 vb[4];
  auto loadB = [&](int k0) {
#pragma unroll
    for (int i = 0; i < 4; ++i)
      vb[i] = *(const float4*)(dwe + (size_t)(k0 + kt * 4 + i) * H_);
  };
  auto writeB = [&](int buf) {
#pragma unroll
    for (int j = 0; j < 4; ++j) {
      int n = nt * 4 + j;
      unsigned u0 = pk2bf(((const float*)&vb[0])[j], ((const float*)&vb[1])[j]);
      unsigned u1 = pk2bf(((const float*)&vb[2])[j], ((const float*)&vb[3])[j]);
      quad_st(&Bs[buf][0], n, kt, u0, u1);
    }
  };

  int mh = w >> 1, nh = w & 1;
  int m = lane & 15, qf = lane >> 4;
  f32x4 acc[2][2] = {};                   // [mt][ntc]

  issueA(0, 0);
  loadB(0);
  writeB(0);
  int cur = 0;
  const int niter = I_ / 64;
#pragma unroll 1
  for (int it = 0; it < niter; ++it) {
    __syncthreads();
    if (it + 1 < niter) { issueA(cur ^ 1, (it + 1) * 64); loadB((it + 1) * 64); }
    const unsigned short* a_ = &As[cur][0];
    const unsigned short* b_ = &Bs[cur][0];
#pragma unroll
    for (int kk = 0; kk < 2; ++kk) {
      int o = kk * 4 + qf;
      bf16x8 af0 = frag_ld(a_, mh * 32 + m,      o);
      bf16x8 af1 = frag_ld(a_, mh * 32 + 16 + m, o);
      bf16x8 bf0 = frag_ld(b_, nh * 32 + m,      o);
      bf16x8 bf1 = frag_ld(b_, nh * 32 + 16 + m, o);
      acc[0][0] = MFMA_BF16_16x16x32(af0, bf0, acc[0][0], 0, 0, 0);
      acc[0][1] = MFMA_BF16_16x16x32(af0, bf1, acc[0][1], 0, 0, 0);
      acc[1][0] = MFMA_BF16_16x16x32(af1, bf0, acc[1][0], 0, 0, 0);
      acc[1][1] = MFMA_BF16_16x16x32(af1, bf1, acc[1][1], 0, 0, 0);
    }
    if (it + 1 < niter) writeB(cur ^ 1);
    cur ^= 1;
  }

  // epilogue: out[token] += rw * fc2  (out zeroed by prep)
#pragma unroll
  for (int mt = 0; mt < 2; ++mt)
#pragma unroll
    for (int r = 0; r < 4; ++r) {
      int prow = row0 + mh * 32 + mt * 16 + qf * 4 + r;
      if (prow < rend) {
        int pair = rows[prow];
        float rw = RW[pair];
        float* orow = out + (size_t)(pair >> 1) * H_ + c0 + nh * 32 + m;
        atomicAdd(orow,      rw * acc[mt][0][r]);
        atomicAdd(orow + 16, rw * acc[mt][1][r]);
      }
    }
}

// ------------------------------------------------------------- launcher ----
extern "C" void kernel_launch(void* const* d_in, const int* in_sizes, int n_in,
                              void* d_out, int out_size, void* d_ws, size_t ws_size,
                              hipStream_t stream) {
  const float* X   = (const float*)d_in[0];
  const float* RW  = (const float*)d_in[1];
  const float* GUP = (const float*)d_in[2];
  const float* DWN = (const float*)d_in[3];
  const int*   SEL = (const int*)d_in[4];
  float* out = (float*)d_out;

  char* ws = (char*)d_ws;
  int* offs = (int*)ws;                                   // 64 B
  int* rows = (int*)(ws + 1024);                          // 8 KB
  unsigned short* Xb  = (unsigned short*)(ws + 16384);    // 4 MB bf16
  unsigned short* act = (unsigned short*)(ws + 16384 + 4194304);  // 3 MB bf16

  hipLaunchKernelGGL(prep_kernel, dim3(2049), dim3(256), 0, stream,
                     X, Xb, out, SEL, offs, rows);
  hipLaunchKernelGGL(fc1_mfma, dim3(24, E_ * SLOTS_), dim3(256), 0, stream,
                     Xb, GUP, offs, rows, act);
  hipLaunchKernelGGL(fc2_mfma, dim3(32, E_ * SLOTS_), dim3(256), 0, stream,
                     act, DWN, RW, offs, rows, out);
}